// Round 1
// 485.745 us; speedup vs baseline: 1.1782x; 1.1782x over previous
//
#include <hip/hip_runtime.h>

// KnowldgeShifter: N=32, K=32, T=128, H=768
// Outputs (flat float32, concatenated):
//   score          (N,K)     = 1024      @ 0
//   shifted_encoded(N,T,H)   = 3145728   @ 1024
//   shifted_mask   (N,T)     = 4096      @ 3146752
//   shifted_use    (N,H)     = 24576     @ 3150848
//   shifted_index  (N,T)     = 4096      @ 3175424
// total out_size = 3179520
//
// R1 finding: bool inputs (pool_mask, ck_mask) are materialized as int32
// (4 B/elem) — byte-indexing them produced spurious NEGINF. Cast as const int*.
//
// R2 (this round): the two ~250us fillBufferAligned dispatches in the timed
// region are the harness's 1.5 GiB ws poison — a ~501us floor we cannot touch.
// Kernel-side residual ~71us was dominated by k1's TA-divergent Wcqk reads
// (thread-per-row => 64 distinct cache lines per wave load) on only 48 CUs.
// Rewritten as wave-per-(2g x 8n)-tile with lanes along K: every global load
// is wave-contiguous (1 KiB), 1536 waves spread over all 256 CUs, butterfly
// shfl_xor reduction. k2 splits the g-reduction 4-way (192 blocks) into
// w_part[4][N][H]; k3 sums the partials while staging wl.

#define NN 32
#define KK 32
#define TT 128
#define HH 768
#define HH2 1536
#define NEGINF_F (-1e20f)

#define OUT_SCORE 0
#define OUT_ENC   1024
#define OUT_MASK  3146752
#define OUT_USE   3150848
#define OUT_IDX   3175424

// gather work partition (in 0..800767):
//   [0, 786432)        encoded float4 copies
//   [786432, 792576)   use float4 copies
//   [792576, 796672)   mask ints -> float
//   [796672, 800768)   token ints -> float
#define GW_ENC 786432
#define GW_USE 792576
#define GW_MSK 796672
#define GW_TOT 800768

#define VBLK 384   // v-compute blocks in k1 (1536 waves = 384 g-pairs x 4 n-blocks)

// Kernel 1: blocks [0,384) compute v[n,g] = cqk_pro via coalesced wave-tiles;
//           blocks [384,384+3128) do the label-gather (BW-bound, overlaps).
__global__ __launch_bounds__(256) void k1_v_gather(
    const float* __restrict__ ce1,   // (N,3,H)
    const float* __restrict__ tku,   // (N,H)
    const float* __restrict__ pe0,   // (N,K,T,H)
    const float* __restrict__ pe1,   // (N,K,H)
    const int* __restrict__ pmask,   // (N,K,T) bool-as-int32
    const int* __restrict__ label,   // (N,)
    const int* __restrict__ ptok,    // (N,K,T)
    const float* __restrict__ Wcqk,  // (H,2H)
    const float* __restrict__ bcqk,  // (H,)
    float* __restrict__ v,           // ws: (N,H)
    float* __restrict__ out)
{
    int b = blockIdx.x;
    if (b < VBLK) {
        // wave wid computes v[nb*8 .. nb*8+7][2*gp .. 2*gp+1]
        int wid  = (b << 2) + (threadIdx.x >> 6);   // 0..1535
        int lane = threadIdx.x & 63;
        int gp = wid >> 2;                          // 0..383
        int nb = wid & 3;                           // 0..3
        int g0 = gp << 1, g1 = g0 + 1;
        const float4* w0 = (const float4*)(Wcqk + (size_t)g0 * HH2);
        const float4* w1 = (const float4*)(Wcqk + (size_t)g1 * HH2);
        float a0[8], a1[8];
#pragma unroll
        for (int i = 0; i < 8; ++i) { a0[i] = 0.f; a1[i] = 0.f; }
        // lanes stride K as float4: j = lane + 64*s, s=0..2 covers 192 float4
        // per half-row. First half: query (ce1[:,2,:]); second: tracked (tku).
#pragma unroll
        for (int s = 0; s < 3; ++s) {
            int j = lane + (s << 6);
            float4 wa = w0[j];
            float4 wb = w1[j];
#pragma unroll
            for (int i = 0; i < 8; ++i) {
                int n = (nb << 3) + i;
                float4 x = ((const float4*)(ce1 + ((size_t)n * 3 + 2) * HH))[j];
                a0[i] = fmaf(wa.w, x.w, fmaf(wa.z, x.z, fmaf(wa.y, x.y, fmaf(wa.x, x.x, a0[i]))));
                a1[i] = fmaf(wb.w, x.w, fmaf(wb.z, x.z, fmaf(wb.y, x.y, fmaf(wb.x, x.x, a1[i]))));
            }
        }
#pragma unroll
        for (int s = 0; s < 3; ++s) {
            int j = lane + (s << 6);
            float4 wa = w0[192 + j];
            float4 wb = w1[192 + j];
#pragma unroll
            for (int i = 0; i < 8; ++i) {
                int n = (nb << 3) + i;
                float4 x = ((const float4*)(tku + (size_t)n * HH))[j];
                a0[i] = fmaf(wa.w, x.w, fmaf(wa.z, x.z, fmaf(wa.y, x.y, fmaf(wa.x, x.x, a0[i]))));
                a1[i] = fmaf(wb.w, x.w, fmaf(wb.z, x.z, fmaf(wb.y, x.y, fmaf(wb.x, x.x, a1[i]))));
            }
        }
        // butterfly reduce the K-dim across the 64 lanes
#pragma unroll
        for (int m = 1; m < 64; m <<= 1) {
#pragma unroll
            for (int i = 0; i < 8; ++i) {
                a0[i] += __shfl_xor(a0[i], m, 64);
                a1[i] += __shfl_xor(a1[i], m, 64);
            }
        }
        if (lane == 0) {
            float bb0 = bcqk[g0], bb1 = bcqk[g1];
#pragma unroll
            for (int i = 0; i < 8; ++i) {
                int n = (nb << 3) + i;
                v[n * HH + g0] = a0[i] + bb0;
                v[n * HH + g1] = a1[i] + bb1;
            }
        }
    } else {
        int wid = (b - VBLK) * 256 + threadIdx.x;  // 0..800767 exactly
        if (wid < GW_ENC) {
            // shifted_encoded: float4 copy of pool_encoded_0[n, label[n], :, :]
            int n = wid / 24576;                 // T*H/4 = 24576 float4 per n
            int r = wid - n * 24576;
            int id = label[n];
            float4 val = ((const float4*)pe0)[(size_t)(n * KK + id) * 24576 + r];
            ((float4*)(out + OUT_ENC))[wid] = val;
        } else if (wid < GW_USE) {
            // shifted_use: float4 copy of pool_encoded_1[n, label[n], :]
            int e = wid - GW_ENC;
            int n = e / 192;                     // H/4 = 192 float4 per n
            int r = e - n * 192;
            int id = label[n];
            float4 val = ((const float4*)pe1)[(size_t)(n * KK + id) * 192 + r];
            ((float4*)(out + OUT_USE))[e] = val;
        } else if (wid < GW_MSK) {
            // shifted_mask: int32 bool -> float
            int e = wid - GW_USE;
            int n = e / TT;
            int t = e - n * TT;
            int id = label[n];
            out[OUT_MASK + e] = pmask[(size_t)(n * KK + id) * TT + t] ? 1.0f : 0.0f;
        } else {
            // shifted_index: int -> float (exact, tokens < 2^24)
            int e = wid - GW_MSK;
            int n = e / TT;
            int t = e - n * TT;
            int id = label[n];
            out[OUT_IDX + e] = (float)ptok[(size_t)(n * KK + id) * TT + t];
        }
    }
}

// Kernel 2: w_part[gs][n][h] = sum_{g in chunk gs} v[n,g] * W_k[g,h]
// 192 blocks = 48 (pair,h) x 4 g-chunks of 192. Wk loads coalesced across h.
__global__ __launch_bounds__(256) void k2_w(
    const float* __restrict__ Wk,    // (H,H)
    const float* __restrict__ v,     // (N,H)
    float* __restrict__ wpart)       // ws: (4,N,H)
{
    int b = blockIdx.x;                          // 0..191
    int gs = b & 3;                              // g-chunk
    int t = (b >> 2) * 256 + threadIdx.x;        // 0..12287
    int pair = t / HH;                           // 0..15
    int h = t - pair * HH;                       // consecutive h -> coalesced Wk
    int n0 = pair, n1 = pair + 16;
    const float4* v0 = (const float4*)(v + (size_t)n0 * HH) + gs * 48;
    const float4* v1 = (const float4*)(v + (size_t)n1 * HH) + gs * 48;
    const float* wkb = Wk + (size_t)(gs * 192) * HH + h;
    float a0 = 0.f, a1 = 0.f;
#pragma unroll 4
    for (int g4 = 0; g4 < 48; ++g4) {
        float4 x0 = v0[g4];
        float4 x1 = v1[g4];
        const float* wp = wkb + (size_t)(g4 * 4) * HH;
        float w0 = wp[0];
        float w1 = wp[HH];
        float w2 = wp[2 * HH];
        float w3 = wp[3 * HH];
        a0 = fmaf(x0.w, w3, fmaf(x0.z, w2, fmaf(x0.y, w1, fmaf(x0.x, w0, a0))));
        a1 = fmaf(x1.w, w3, fmaf(x1.z, w2, fmaf(x1.y, w1, fmaf(x1.x, w0, a1))));
    }
    wpart[(size_t)(gs * NN + n0) * HH + h] = a0;
    wpart[(size_t)(gs * NN + n1) * HH + h] = a1;
}

// Kernel 3: score[n,k] = ck_mask ? dot(pe1[n,k,:], w[n,:]) + c[n] : NEGINF
// One block per n; w[n,:] = sum of 4 partials, staged in LDS; c[n] = dot(b_k, v[n,:]).
__global__ __launch_bounds__(256) void k3_score(
    const float* __restrict__ pe1,   // (N,K,H)
    const float* __restrict__ v,     // (N,H)
    const float* __restrict__ wpart, // ws: (4,N,H)
    const float* __restrict__ bk,    // (H,)
    const int* __restrict__ ckm,     // (N,K) bool-as-int32
    float* __restrict__ out)
{
    __shared__ float wl[HH];
    __shared__ float cpart[4];
    int n = blockIdx.x;
    int tid = threadIdx.x;
    int lane = tid & 63;
    int wv = tid >> 6;

    float p = 0.f;
#pragma unroll
    for (int i = 0; i < 3; ++i) {
        int g = tid + 256 * i;
        size_t off = (size_t)n * HH + g;
        float s = wpart[off] + wpart[(size_t)NN * HH + off]
                + wpart[(size_t)2 * NN * HH + off] + wpart[(size_t)3 * NN * HH + off];
        wl[g] = s;
        p += bk[g] * v[off];
    }
#pragma unroll
    for (int m = 1; m < 64; m <<= 1) p += __shfl_xor(p, m, 64);
    if (lane == 0) cpart[wv] = p;
    __syncthreads();
    float c = cpart[0] + cpart[1] + cpart[2] + cpart[3];

    for (int k = wv; k < KK; k += 4) {
        const float* row = pe1 + (size_t)(n * KK + k) * HH;
        float acc = 0.f;
#pragma unroll
        for (int i = 0; i < 12; ++i) {
            int h = lane + 64 * i;               // coalesced across lanes
            acc += row[h] * wl[h];
        }
#pragma unroll
        for (int m = 1; m < 64; m <<= 1) acc += __shfl_xor(acc, m, 64);
        if (lane == 0) {
            float s = acc + c;
            out[OUT_SCORE + n * KK + k] = ckm[n * KK + k] ? s : NEGINF_F;
        }
    }
}

extern "C" void kernel_launch(void* const* d_in, const int* in_sizes, int n_in,
                              void* d_out, int out_size, void* d_ws, size_t ws_size,
                              hipStream_t stream)
{
    const float* ce1  = (const float*)d_in[0];
    const float* tku  = (const float*)d_in[1];
    const float* pe0  = (const float*)d_in[2];
    const float* pe1  = (const float*)d_in[3];
    const int* pmask  = (const int*)d_in[4];
    const int* ckm    = (const int*)d_in[5];
    const int* label  = (const int*)d_in[6];
    const int* ptok   = (const int*)d_in[7];
    const float* Wcqk = (const float*)d_in[8];
    const float* bcqk = (const float*)d_in[9];
    const float* Wk   = (const float*)d_in[10];
    const float* bk   = (const float*)d_in[11];

    float* out = (float*)d_out;
    float* v = (float*)d_ws;             // N*H floats
    float* wpart = v + NN * HH;          // 4*N*H floats (ws total 480 KiB)

    // 384 v-blocks + ceil(800768/256)=3128 gather blocks
    k1_v_gather<<<VBLK + 3128, 256, 0, stream>>>(ce1, tku, pe0, pe1, pmask,
                                                 label, ptok, Wcqk, bcqk, v, out);
    k2_w<<<192, 256, 0, stream>>>(Wk, v, wpart);
    k3_score<<<32, 256, 0, stream>>>(pe1, v, wpart, bk, ckm, out);
}